// Round 2
// baseline (431.989 us; speedup 1.0000x reference)
//
#include <hip/hip_runtime.h>

// WKV scan: B=8, S=2048, E=2048, fp32.
// One thread per (b,e) channel: 16384 threads = 256 blocks x 64 = 1 wave/CU.
// Sequential over t; double-buffered register pipeline (U=32 per half) keeps
// ~64 coalesced wave-loads (16 KB/CU) in flight to satisfy Little's law at
// ~24.6 GB/s/CU with ~900-cycle HBM latency.

#define WKV_B 8
#define WKV_S 2048
#define WKV_E 2048

constexpr int U = 32;

__global__ __launch_bounds__(64) void wkv_scan_kernel(
    const float* __restrict__ td_g, const float* __restrict__ tf_g,
    const float* __restrict__ k_g, const float* __restrict__ v_g,
    float* __restrict__ y_g)
{
    constexpr int S = WKV_S;
    constexpr int E = WKV_E;

    const int c = blockIdx.x * 64 + threadIdx.x;   // channel id in [0, B*E)
    const int b = c >> 11;                          // c / E   (E = 2048)
    const int e = c & (E - 1);                      // c % E

    const float td = td_g[e];
    const float tf = tf_g[e];

    const long base = (long)b * S * E + e;
    const float* __restrict__ kp = k_g + base;
    const float* __restrict__ vp = v_g + base;
    float* __restrict__ yp = y_g + base;

    float aa = 0.0f, bb = 0.0f, eps = 0.0f;

    // Two named register buffers (compile-time indexed only — avoid scratch).
    float kA[U], vA[U], kB[U], vB[U];

#pragma unroll
    for (int i = 0; i < U; ++i) {
        kA[i] = __builtin_nontemporal_load(&kp[i * E]);
        vA[i] = __builtin_nontemporal_load(&vp[i * E]);
    }

    auto step = [&](float kt, float vt, int t) {
        // e1 = exp(tf + kt - eps); y = (aa + vt*e1) / (bb + e1)
        const float e1 = __expf(tf + kt - eps);
        const float y  = __fdividef(fmaf(vt, e1, aa), bb + e1);
        __builtin_nontemporal_store(y, &yp[t * E]);
        // state update
        const float tde  = td + eps;
        const float eps2 = fmaxf(tde, kt);
        const float e2   = __expf(tde - eps2);
        const float e3   = __expf(kt - eps2);
        aa = fmaf(aa, e2, vt * e3);
        bb = fmaf(bb, e2, e3);
        eps = eps2;
    };

    for (int t0 = 0; t0 < S; t0 += 2 * U) {
        // Issue loads for half B (t0+U .. t0+2U-1) — always in range:
        // max t0 = S-2U -> loads reach S-1.
#pragma unroll
        for (int i = 0; i < U; ++i) {
            kB[i] = __builtin_nontemporal_load(&kp[(t0 + U + i) * E]);
            vB[i] = __builtin_nontemporal_load(&vp[(t0 + U + i) * E]);
        }
        // Compute half A
#pragma unroll
        for (int i = 0; i < U; ++i) step(kA[i], vA[i], t0 + i);

        // Issue loads for the NEXT half A (t0+2U ..), guarded on last iter.
        if (t0 + 2 * U < S) {
#pragma unroll
            for (int i = 0; i < U; ++i) {
                kA[i] = __builtin_nontemporal_load(&kp[(t0 + 2 * U + i) * E]);
                vA[i] = __builtin_nontemporal_load(&vp[(t0 + 2 * U + i) * E]);
            }
        }
        // Compute half B
#pragma unroll
        for (int i = 0; i < U; ++i) step(kB[i], vB[i], t0 + U + i);
    }
}

extern "C" void kernel_launch(void* const* d_in, const int* in_sizes, int n_in,
                              void* d_out, int out_size, void* d_ws, size_t ws_size,
                              hipStream_t stream) {
    // setup_inputs order: batch_size, seq_len, embedding_dim,
    //                     time_decay, time_first, k, v
    const float* td = (const float*)d_in[3];
    const float* tf = (const float*)d_in[4];
    const float* k  = (const float*)d_in[5];
    const float* v  = (const float*)d_in[6];
    float* y        = (float*)d_out;
    (void)in_sizes; (void)n_in; (void)out_size; (void)d_ws; (void)ws_size;

    dim3 grid((WKV_B * WKV_E) / 64);
    dim3 block(64);
    hipLaunchKernelGGL(wkv_scan_kernel, grid, block, 0, stream, td, tf, k, v, y);
}

// Round 3
// 372.898 us; speedup vs baseline: 1.1585x; 1.1585x over previous
//
#include <hip/hip_runtime.h>

// WKV scan, B=8, S=2048, E=2048, fp32 — chunked 3-pass parallel scan.
//
// R2 post-mortem: single-pass (1 wave/CU) was latency-bound: 201us,
// 16% HBM, 16% VALUBusy, occupancy 2.9%. Per-wave ILP is capped by
// vmcnt<=63 outstanding loads; effective latency too high. Fix = TLP:
// chunk the time axis (C=16, L=128) -> 16 waves/CU in passes 1 & 3.
//
// Math: unnormalized state A_t = A_{t-1}*e^td + v_t*e^kt, so incoming
// state decays by exactly e^{L*td} across a chunk; summaries combine
// with the standard max-stabilized log-sum-exp fold. eps_c >= L*td
// always, so a (0,0,0)-seeded fold is exact on the first chunk.

#define B_ 8
#define S_ 2048
#define E_ 2048
constexpr int BE = B_ * E_;    // 16384 channels (2^14)
constexpr int CH = 16;         // chunks
constexpr int CL = S_ / CH;    // 128 steps per chunk

// ---------------- pass 1: per-chunk summaries from zero state ----------------
__global__ __launch_bounds__(64) void wkv_pass1(
    const float* __restrict__ td_g,
    const float* __restrict__ k_g, const float* __restrict__ v_g,
    float* __restrict__ sa, float* __restrict__ sb, float* __restrict__ se)
{
    const int gid = blockIdx.x * 64 + threadIdx.x;
    const int j = gid >> 14;            // chunk 0..CH-2 (last chunk's summary unused)
    const int c = gid & (BE - 1);
    const int b = c >> 11;
    const int e = c & (E_ - 1);
    const float td = td_g[e];
    const long base = (long)b * S_ * E_ + (long)(j * CL) * E_ + e;
    const float* __restrict__ kp = k_g + base;
    const float* __restrict__ vp = v_g + base;

    float aa = 0.f, bb = 0.f, eps = 0.f;
    constexpr int U = 8;
    float kA[U], vA[U], kB[U], vB[U];
#pragma unroll
    for (int i = 0; i < U; ++i) { kA[i] = kp[i * E_]; vA[i] = vp[i * E_]; }

    auto st = [&](float kt, float vt) {
        const float tde = td + eps;
        const float m   = fmaxf(tde, kt);
        const float p   = __expf(tde - m);
        const float q   = __expf(kt - m);
        aa = fmaf(aa, p, vt * q);
        bb = fmaf(bb, p, q);
        eps = m;
    };

    for (int t0 = 0; t0 < CL; t0 += 2 * U) {
#pragma unroll
        for (int i = 0; i < U; ++i) { kB[i] = kp[(t0 + U + i) * E_]; vB[i] = vp[(t0 + U + i) * E_]; }
#pragma unroll
        for (int i = 0; i < U; ++i) st(kA[i], vA[i]);
        if (t0 + 2 * U < CL) {
#pragma unroll
            for (int i = 0; i < U; ++i) { kA[i] = kp[(t0 + 2*U + i) * E_]; vA[i] = vp[(t0 + 2*U + i) * E_]; }
        }
#pragma unroll
        for (int i = 0; i < U; ++i) st(kB[i], vB[i]);
    }
    sa[j * BE + c] = aa;
    sb[j * BE + c] = bb;
    se[j * BE + c] = eps;
}

// ---------------- pass 2: fold summaries -> per-chunk incoming states --------
__global__ __launch_bounds__(64) void wkv_pass2(
    const float* __restrict__ td_g,
    const float* __restrict__ sa, const float* __restrict__ sb, const float* __restrict__ se,
    float* __restrict__ ia, float* __restrict__ ib, float* __restrict__ ie)
{
    const int c = blockIdx.x * 64 + threadIdx.x;   // 0..BE-1
    const int e = c & (E_ - 1);
    const float Ltd = (float)CL * td_g[e];

    float aa = 0.f, bb = 0.f, eps = 0.f;
    ia[c] = 0.f; ib[c] = 0.f; ie[c] = 0.f;         // chunk 0 starts from zero
#pragma unroll
    for (int j = 1; j < CH; ++j) {
        const float a_c = sa[(j - 1) * BE + c];
        const float b_c = sb[(j - 1) * BE + c];
        const float e_c = se[(j - 1) * BE + c];
        const float ed  = eps + Ltd;
        const float ne  = fmaxf(ed, e_c);
        const float f1  = __expf(ed - ne);
        const float f2  = __expf(e_c - ne);
        aa = aa * f1 + a_c * f2;
        bb = bb * f1 + b_c * f2;
        eps = ne;
        ia[j * BE + c] = aa;
        ib[j * BE + c] = bb;
        ie[j * BE + c] = eps;
    }
}

// ---------------- pass 3: replay each chunk with true incoming state ---------
__global__ __launch_bounds__(64) void wkv_pass3(
    const float* __restrict__ td_g, const float* __restrict__ tf_g,
    const float* __restrict__ k_g, const float* __restrict__ v_g,
    const float* __restrict__ ia, const float* __restrict__ ib, const float* __restrict__ ie,
    float* __restrict__ y_g)
{
    const int gid = blockIdx.x * 64 + threadIdx.x;
    const int j = gid >> 14;            // chunk 0..CH-1
    const int c = gid & (BE - 1);
    const int b = c >> 11;
    const int e = c & (E_ - 1);
    const float td = td_g[e];
    const float tf = tf_g[e];
    const long base = (long)b * S_ * E_ + (long)(j * CL) * E_ + e;
    const float* __restrict__ kp = k_g + base;
    const float* __restrict__ vp = v_g + base;
    float* __restrict__ yp = y_g + base;

    float aa = ia[j * BE + c];
    float bb = ib[j * BE + c];
    float eps = ie[j * BE + c];

    constexpr int U = 8;
    float kA[U], vA[U], kB[U], vB[U];
#pragma unroll
    for (int i = 0; i < U; ++i) { kA[i] = kp[i * E_]; vA[i] = vp[i * E_]; }

    auto st = [&](float kt, float vt, int t) {
        const float e1 = __expf(tf + kt - eps);
        const float y  = __fdividef(fmaf(vt, e1, aa), bb + e1);
        __builtin_nontemporal_store(y, &yp[t * E_]);
        const float tde = td + eps;
        const float m   = fmaxf(tde, kt);
        const float p   = __expf(tde - m);
        const float q   = __expf(kt - m);
        aa = fmaf(aa, p, vt * q);
        bb = fmaf(bb, p, q);
        eps = m;
    };

    for (int t0 = 0; t0 < CL; t0 += 2 * U) {
#pragma unroll
        for (int i = 0; i < U; ++i) { kB[i] = kp[(t0 + U + i) * E_]; vB[i] = vp[(t0 + U + i) * E_]; }
#pragma unroll
        for (int i = 0; i < U; ++i) st(kA[i], vA[i], t0 + i);
        if (t0 + 2 * U < CL) {
#pragma unroll
            for (int i = 0; i < U; ++i) { kA[i] = kp[(t0 + 2*U + i) * E_]; vA[i] = vp[(t0 + 2*U + i) * E_]; }
        }
#pragma unroll
        for (int i = 0; i < U; ++i) st(kB[i], vB[i], t0 + U + i);
    }
}

// ---------------- fallback: R2 single-pass kernel (if ws too small) ----------
__global__ __launch_bounds__(64) void wkv_single(
    const float* __restrict__ td_g, const float* __restrict__ tf_g,
    const float* __restrict__ k_g, const float* __restrict__ v_g,
    float* __restrict__ y_g)
{
    const int c = blockIdx.x * 64 + threadIdx.x;
    const int b = c >> 11;
    const int e = c & (E_ - 1);
    const float td = td_g[e];
    const float tf = tf_g[e];
    const long base = (long)b * S_ * E_ + e;
    const float* __restrict__ kp = k_g + base;
    const float* __restrict__ vp = v_g + base;
    float* __restrict__ yp = y_g + base;
    float aa = 0.f, bb = 0.f, eps = 0.f;
    for (int t = 0; t < S_; ++t) {
        const float kt = kp[t * E_], vt = vp[t * E_];
        const float e1 = __expf(tf + kt - eps);
        yp[t * E_] = __fdividef(fmaf(vt, e1, aa), bb + e1);
        const float tde = td + eps;
        const float m = fmaxf(tde, kt);
        const float p = __expf(tde - m);
        const float q = __expf(kt - m);
        aa = fmaf(aa, p, vt * q);
        bb = fmaf(bb, p, q);
        eps = m;
    }
}

extern "C" void kernel_launch(void* const* d_in, const int* in_sizes, int n_in,
                              void* d_out, int out_size, void* d_ws, size_t ws_size,
                              hipStream_t stream) {
    // setup_inputs order: batch_size, seq_len, embedding_dim,
    //                     time_decay, time_first, k, v
    const float* td = (const float*)d_in[3];
    const float* tf = (const float*)d_in[4];
    const float* k  = (const float*)d_in[5];
    const float* v  = (const float*)d_in[6];
    float* y        = (float*)d_out;
    (void)in_sizes; (void)n_in; (void)out_size;

    const size_t arr = (size_t)CH * BE * sizeof(float);   // 1 MiB per array
    if (ws_size < 6 * arr) {
        // workspace too small for summaries — fall back to single-pass
        hipLaunchKernelGGL(wkv_single, dim3(BE / 64), dim3(64), 0, stream, td, tf, k, v, y);
        return;
    }
    float* sa = (float*)d_ws;
    float* sb = sa + CH * BE;
    float* se = sb + CH * BE;
    float* ia = se + CH * BE;
    float* ib = ia + CH * BE;
    float* ie = ib + CH * BE;

    hipLaunchKernelGGL(wkv_pass1, dim3((CH - 1) * BE / 64), dim3(64), 0, stream,
                       td, k, v, sa, sb, se);
    hipLaunchKernelGGL(wkv_pass2, dim3(BE / 64), dim3(64), 0, stream,
                       td, sa, sb, se, ia, ib, ie);
    hipLaunchKernelGGL(wkv_pass3, dim3(CH * BE / 64), dim3(64), 0, stream,
                       td, tf, k, v, ia, ib, ie, y);
}